// Round 7
// baseline (252.218 us; speedup 1.0000x reference)
//
#include <hip/hip_runtime.h>

#define H 2048

// inter-kernel scratch (device globals; fully rewritten every call before read)
__device__ __align__(16) float g_p1[4 * H];   // layer-1 recurrent partial + both biases
__device__ __align__(16) float g_h0[H];       // layer-0 new h
__device__ __align__(16) float g_h1[H];       // layer-1 new h
__device__ __align__(16) float g_hid[13 * 64];// head hidden activations

__device__ __forceinline__ float sg(float x) { return 1.f / (1.f + __expf(-x)); }

__device__ __forceinline__ float wred(float x) {
    #pragma unroll
    for (int o = 32; o > 0; o >>= 1) x += __shfl_down(x, o);
    return x;
}

// async global->LDS DMA: 16B per lane, 1KB per call per wave.
// g = per-lane global address (base + lane*16B); l = WAVE-UNIFORM lds chunk base;
// lane i lands at l + i*16B (contiguous chunk).
__device__ __forceinline__ void gl_lds(const float* g, float* l) {
    __builtin_amdgcn_global_load_lds(
        (const __attribute__((address_space(1))) void*)g,
        (__attribute__((address_space(3))) void*)l,
        16, 0, 0);
}

// per-wave dot from LDS: row[2048] . vec[2048]
__device__ __forceinline__ float dot_lds(const float* row, const float* vec, int lane) {
    float acc = 0.f;
    #pragma unroll
    for (int c = 0; c < 8; c++) {
        float4 a = *reinterpret_cast<const float4*>(row + c * 256 + lane * 4);
        float4 v = *reinterpret_cast<const float4*>(vec + c * 256 + lane * 4);
        acc = fmaf(a.x, v.x, acc); acc = fmaf(a.y, v.y, acc);
        acc = fmaf(a.z, v.z, acc); acc = fmaf(a.w, v.w, acc);
    }
    return acc;
}

// K1: blocks 0..2047    -> layer-0 LSTM cell j=b (wave w = gate row j+w*H)
//     blocks 2048..4095 -> Whh1 recurrent partials (4 rows/block, 1/wave)
// All weight rows + the h vector staged via async global_load_lds.
__global__ __launch_bounds__(256) void k1(
    const float* __restrict__ lap, const int* __restrict__ idx,
    const float* __restrict__ h_s, const float* __restrict__ c_s,
    const float* __restrict__ e_team, const float* __restrict__ e_trk,
    const float* __restrict__ e_drv, const float* __restrict__ e_cmp,
    const float* __restrict__ Wih0, const float* __restrict__ Whh0,
    const float* __restrict__ bih0, const float* __restrict__ bhh0,
    const float* __restrict__ Whh1, const float* __restrict__ bih1,
    const float* __restrict__ bhh1, float* __restrict__ out)
{
    __shared__ float rows[4][H];   // 32 KB
    __shared__ float vec[H];       // 8 KB
    __shared__ float xsh[96];
    __shared__ float gsh[4];
    int tid = threadIdx.x, w = tid >> 6, lane = tid & 63;
    int b = blockIdx.x;
    bool l0 = b < 2048;

    long row = l0 ? (b + (long)w * H) : ((long)(b - 2048) * 4 + w);
    const float* rp  = (l0 ? Whh0 : Whh1) + row * H;
    const float* src = l0 ? h_s : (h_s + H);

    // issue all async stages back-to-back: 8KB row/wave + 2KB of vec/wave
    #pragma unroll
    for (int c = 0; c < 8; c++) gl_lds(rp + c * 256 + lane * 4, &rows[w][c * 256]);
    #pragma unroll
    for (int c = 0; c < 2; c++) {
        int cc = w * 2 + c;
        gl_lds(src + cc * 256 + lane * 4, &vec[cc * 256]);
    }

    // independent small loads overlap the DMA
    float wv0 = 0.f, wv1 = 0.f;
    if (l0) {
        const float* wr = Wih0 + row * 92;
        wv0 = wr[lane];
        if (lane < 28) wv1 = wr[lane + 64];
        if (tid < 92) {
            float v;
            if (tid < 60)      v = lap[tid];
            else if (tid < 68) v = e_team[idx[3] * 8 + tid - 60];
            else if (tid < 76) v = e_trk [idx[2] * 8 + tid - 68];
            else if (tid < 84) v = e_drv [idx[1] * 8 + tid - 76];
            else               v = e_cmp [idx[0] * 8 + tid - 84];
            xsh[tid] = v;
        }
    }
    __syncthreads();   // drains vmcnt: all LDS staging complete

    float acc = dot_lds(rows[w], vec, lane);
    if (l0) {
        float p = xsh[lane] * wv0;
        if (lane < 28) p += xsh[lane + 64] * wv1;
        acc += p;
    }
    acc = wred(acc);

    if (l0) {
        if (lane == 0) gsh[w] = acc + bih0[row] + bhh0[row];
        __syncthreads();
        if (tid == 0) {
            int j = b;
            float gi = gsh[0], gf = gsh[1], gg = gsh[2], go = gsh[3];
            float cp = c_s[j];
            float cn = sg(gf) * cp + sg(gi) * tanhf(gg);
            float hn = sg(go) * tanhf(cn);
            out[j]         = hn;   // new_h[0]
            out[2 * H + j] = cn;   // new_c[0]
            g_h0[j] = hn;
        }
    } else {
        if (lane == 0) g_p1[row] = acc + bih1[row] + bhh1[row];
    }
}

// K2: layer-1 LSTM cell j=b; wave w = gate row j+w*H. Async staging of Wih1 rows + g_h0.
__global__ __launch_bounds__(256) void k2(
    const float* __restrict__ Wih1, const float* __restrict__ c_s,
    float* __restrict__ out)
{
    __shared__ float rows[4][H];
    __shared__ float vec[H];
    __shared__ float gsh[4];
    int tid = threadIdx.x, w = tid >> 6, lane = tid & 63;
    int j = blockIdx.x;
    long row = j + (long)w * H;
    const float* rp = Wih1 + row * H;
    #pragma unroll
    for (int c = 0; c < 8; c++) gl_lds(rp + c * 256 + lane * 4, &rows[w][c * 256]);
    #pragma unroll
    for (int c = 0; c < 2; c++) {
        int cc = w * 2 + c;
        gl_lds(g_h0 + cc * 256 + lane * 4, &vec[cc * 256]);
    }
    __syncthreads();

    float acc = wred(dot_lds(rows[w], vec, lane));
    if (lane == 0) gsh[w] = acc + g_p1[row];
    __syncthreads();
    if (tid == 0) {
        float gi = gsh[0], gf = gsh[1], gg = gsh[2], go = gsh[3];
        float cp = c_s[H + j];
        float cn = sg(gf) * cp + sg(gi) * tanhf(gg);
        float hn = sg(go) * tanhf(cn);
        out[H + j]     = hn;   // new_h[1]
        out[3 * H + j] = cn;   // new_c[1]
        g_h1[j] = hn;
    }
}

// K3: fused LayerNorm (redundant per block) + head hidden.
// 208 blocks: head k=b>>4, unit o=(b&15)*4+w. W1 rows staged async during LN.
__global__ __launch_bounds__(256) void k3(
    const float* __restrict__ ln_g, const float* __restrict__ ln_b,
    const float* __restrict__ W1, const float* __restrict__ b1)
{
    __shared__ float rows[4][H];
    __shared__ float ht[H];
    __shared__ float red[8];
    __shared__ float mvs[2];
    int tid = threadIdx.x, w = tid >> 6, lane = tid & 63;
    int k = blockIdx.x >> 4;
    int o = (blockIdx.x & 15) * 4 + w;
    const float* rp = W1 + ((long)k * 64 + o) * H;
    #pragma unroll
    for (int c = 0; c < 8; c++) gl_lds(rp + c * 256 + lane * 4, &rows[w][c * 256]);

    float v[8];
    float s = 0.f, s2 = 0.f;
    #pragma unroll
    for (int i = 0; i < 8; i++) {
        float x = g_h1[tid + i * 256];
        v[i] = x; s += x; s2 += x * x;
    }
    s = wred(s); s2 = wred(s2);
    if (lane == 0) { red[w] = s; red[4 + w] = s2; }
    __syncthreads();
    if (tid == 0) {
        float ts = red[0] + red[1] + red[2] + red[3];
        float t2 = red[4] + red[5] + red[6] + red[7];
        float mu = ts / (float)H;
        float var = t2 / (float)H - mu * mu;
        mvs[0] = mu; mvs[1] = rsqrtf(var + 1e-5f);
    }
    __syncthreads();
    float mu = mvs[0], rs = mvs[1];
    #pragma unroll
    for (int i = 0; i < 8; i++) {
        int e = tid + i * 256;
        ht[e] = (v[i] - mu) * rs * ln_g[e] + ln_b[e];
    }
    __syncthreads();

    float acc = wred(dot_lds(rows[w], ht, lane));
    if (lane == 0) {
        float r = acc + b1[k * 64 + o];
        g_hid[k * 64 + o] = r > 0.f ? r : 0.f;
    }
}

// K4: head output layer (tiny)
__global__ __launch_bounds__(128) void k4(
    const float* __restrict__ W2, const float* __restrict__ b2,
    float* __restrict__ out)
{
    const int HO[13]  = {5,1,1,1,1,1,1,1,9,1,3,1,1};
    const int OFF[13] = {0,5,6,7,8,9,10,11,12,21,22,25,26};
    int t = threadIdx.x;
    if (t >= 117) return;
    int k = t / 9, p = t % 9;
    if (p >= HO[k]) return;
    const float* wr = W2 + ((long)k * 9 + p) * 64;
    const float* hp = g_hid + k * 64;
    float acc = b2[k * 9 + p];
    #pragma unroll
    for (int o = 0; o < 64; o++) acc = fmaf(hp[o], wr[o], acc);
    out[4 * H + OFF[k] + p] = acc;
}

extern "C" void kernel_launch(void* const* d_in, const int* in_sizes, int n_in,
                              void* d_out, int out_size, void* d_ws, size_t ws_size,
                              hipStream_t stream) {
    const float* lap    = (const float*)d_in[0];
    const int*   idx    = (const int*)  d_in[1];
    const float* h_s    = (const float*)d_in[2];
    const float* c_s    = (const float*)d_in[3];
    const float* e_team = (const float*)d_in[4];
    const float* e_trk  = (const float*)d_in[5];
    const float* e_drv  = (const float*)d_in[6];
    const float* e_cmp  = (const float*)d_in[7];
    const float* Wih0   = (const float*)d_in[8];
    const float* Whh0   = (const float*)d_in[9];
    const float* bih0   = (const float*)d_in[10];
    const float* bhh0   = (const float*)d_in[11];
    const float* Wih1   = (const float*)d_in[12];
    const float* Whh1   = (const float*)d_in[13];
    const float* bih1   = (const float*)d_in[14];
    const float* bhh1   = (const float*)d_in[15];
    const float* ln_g   = (const float*)d_in[16];
    const float* ln_b   = (const float*)d_in[17];
    const float* hW1    = (const float*)d_in[18];
    const float* hb1    = (const float*)d_in[19];
    const float* hW2    = (const float*)d_in[20];
    const float* hb2    = (const float*)d_in[21];
    float* out = (float*)d_out;

    k1<<<4096, 256, 0, stream>>>(lap, idx, h_s, c_s, e_team, e_trk, e_drv, e_cmp,
                                 Wih0, Whh0, bih0, bhh0, Whh1, bih1, bhh1, out);
    k2<<<2048, 256, 0, stream>>>(Wih1, c_s, out);
    k3<<<208, 256, 0, stream>>>(ln_g, ln_b, hW1, hb1);
    k4<<<1, 128, 0, stream>>>(hW2, hb2, out);
}

// Round 8
// 251.371 us; speedup vs baseline: 1.0034x; 1.0034x over previous
//
#include <hip/hip_runtime.h>

#define H 2048

// inter-kernel scratch (device globals; fully rewritten every call before read)
__device__ __align__(16) float g_p1[4 * H];   // layer-1 recurrent partial (pre-bias)
__device__ __align__(16) float g_h0[H];       // layer-0 new h
__device__ __align__(16) float g_h1[H];       // layer-1 new h
__device__ __align__(16) float g_hid[13 * 64];// head hidden activations

// s_waitcnt imms: lgkm=15 (no wait), exp=7 (no wait), vmcnt in [3:0]
#define WAIT_VM8 0xF78
#define WAIT_VM0 0xF70

__device__ __forceinline__ float sg(float x) { return 1.f / (1.f + __expf(-x)); }

__device__ __forceinline__ float wred(float x) {
    #pragma unroll
    for (int o = 32; o > 0; o >>= 1) x += __shfl_down(x, o);
    return x;
}

// async global->LDS DMA: 16B/lane, 1KB per call per wave; l is wave-uniform base,
// lane i lands at l + i*16B
__device__ __forceinline__ void gl_lds(const float* g, float* l) {
    __builtin_amdgcn_global_load_lds(
        (const __attribute__((address_space(1))) void*)g,
        (__attribute__((address_space(3))) void*)l,
        16, 0, 0);
}

// K1: grid 512 (all co-resident), wave-autonomous. Wave wid = blockIdx*4+w owns
// cell wid: streams 8 rows (Whh0 gates 0-3 against h_s[0]; Whh1 gates 0-3 against
// h_s[1]) through a private double-buffered LDS pair with vmcnt(8) pipelining,
// then lane 0 completes the full layer-0 cell + p1 partials.
__global__ __launch_bounds__(256) void k1(
    const float* __restrict__ lap, const int* __restrict__ idx,
    const float* __restrict__ h_s, const float* __restrict__ c_s,
    const float* __restrict__ e_team, const float* __restrict__ e_trk,
    const float* __restrict__ e_drv, const float* __restrict__ e_cmp,
    const float* __restrict__ Wih0, const float* __restrict__ Whh0,
    const float* __restrict__ bih0, const float* __restrict__ bhh0,
    const float* __restrict__ Whh1, const float* __restrict__ bih1,
    const float* __restrict__ bhh1, float* __restrict__ out)
{
    __shared__ float buf[4][2][H];   // 64 KB: per-wave double buffer
    int tid = threadIdx.x, w = tid >> 6, lane = tid & 63;
    int wid = blockIdx.x * 4 + w;    // cell index 0..2047

    // h vectors in registers (lane's 32+32 elems, matching DMA chunk layout)
    float4 va[8], vb[8];
    #pragma unroll
    for (int c = 0; c < 8; c++) {
        va[c] = *reinterpret_cast<const float4*>(h_s + c * 256 + lane * 4);
        vb[c] = *reinterpret_cast<const float4*>(h_s + H + c * 256 + lane * 4);
    }
    // x-concat gather (per-wave redundant; L1-cached)
    float xa, xb = 0.f;
    {
        int i = lane;
        xa = (i < 60) ? lap[i]
           : (i < 68) ? e_team[idx[3] * 8 + i - 60]
           : (i < 76) ? e_trk [idx[2] * 8 + i - 68]
           : (i < 84) ? e_drv [idx[1] * 8 + i - 76]
                      : e_cmp [idx[0] * 8 + i - 84];
        if (lane < 28) {
            int j2 = lane + 64;
            xb = (j2 < 68) ? e_team[idx[3] * 8 + j2 - 60]
               : (j2 < 76) ? e_trk [idx[2] * 8 + j2 - 68]
               : (j2 < 84) ? e_drv [idx[1] * 8 + j2 - 76]
                           : e_cmp [idx[0] * 8 + j2 - 84];
        }
    }

    const float* rp[8];
    #pragma unroll
    for (int k = 0; k < 8; k++) {
        const float* W = (k < 4) ? Whh0 : Whh1;
        rp[k] = W + ((long)wid + (long)(k & 3) * H) * H;
    }

    // prologue: issue row 0
    #pragma unroll
    for (int c = 0; c < 8; c++) gl_lds(rp[0] + c * 256 + lane * 4, &buf[w][0][c * 256]);

    float dsum[8];
    #pragma unroll
    for (int k = 0; k < 8; k++) {
        if (k < 7) {
            #pragma unroll
            for (int c = 0; c < 8; c++)
                gl_lds(rp[k + 1] + c * 256 + lane * 4, &buf[w][(k + 1) & 1][c * 256]);
            __builtin_amdgcn_s_waitcnt(WAIT_VM8);   // row k arrived; row k+1 in flight
        } else {
            __builtin_amdgcn_s_waitcnt(WAIT_VM0);
        }
        const float* r = buf[w][k & 1];
        float acc = 0.f;
        #pragma unroll
        for (int c = 0; c < 8; c++) {
            float4 a = *reinterpret_cast<const float4*>(r + c * 256 + lane * 4);
            float4 v = (k < 4) ? va[c] : vb[c];
            acc = fmaf(a.x, v.x, acc); acc = fmaf(a.y, v.y, acc);
            acc = fmaf(a.z, v.z, acc); acc = fmaf(a.w, v.w, acc);
        }
        dsum[k] = acc;
    }

    // gate sums: add Wih0 x-part, reduce
    float gate[4], p1v[4];
    #pragma unroll
    for (int g = 0; g < 4; g++) {
        const float* wr = Wih0 + ((long)wid + (long)g * H) * 92;
        float p = xa * wr[lane] + ((lane < 28) ? xb * wr[lane + 64] : 0.f);
        gate[g] = wred(dsum[g] + p);
        p1v[g]  = wred(dsum[4 + g]);
    }
    if (lane == 0) {
        float gi = gate[0] + bih0[wid]         + bhh0[wid];
        float gf = gate[1] + bih0[wid + H]     + bhh0[wid + H];
        float gg = gate[2] + bih0[wid + 2 * H] + bhh0[wid + 2 * H];
        float go = gate[3] + bih0[wid + 3 * H] + bhh0[wid + 3 * H];
        float cp = c_s[wid];
        float cn = sg(gf) * cp + sg(gi) * tanhf(gg);
        float hn = sg(go) * tanhf(cn);
        out[wid]         = hn;   // new_h[0]
        out[2 * H + wid] = cn;   // new_c[0]
        g_h0[wid] = hn;
        #pragma unroll
        for (int g = 0; g < 4; g++)
            g_p1[wid + g * H] = p1v[g] + bih1[wid + g * H] + bhh1[wid + g * H];
    }
}

// K2: same structure; wave wid streams the 4 Wih1 gate rows of cell wid against
// register-held g_h0, then lane 0 completes layer-1 cell.
__global__ __launch_bounds__(256) void k2(
    const float* __restrict__ Wih1, const float* __restrict__ c_s,
    float* __restrict__ out)
{
    __shared__ float buf[4][2][H];
    int tid = threadIdx.x, w = tid >> 6, lane = tid & 63;
    int wid = blockIdx.x * 4 + w;

    float4 va[8];
    #pragma unroll
    for (int c = 0; c < 8; c++)
        va[c] = *reinterpret_cast<const float4*>(g_h0 + c * 256 + lane * 4);

    const float* rp[4];
    #pragma unroll
    for (int k = 0; k < 4; k++)
        rp[k] = Wih1 + ((long)wid + (long)k * H) * H;

    #pragma unroll
    for (int c = 0; c < 8; c++) gl_lds(rp[0] + c * 256 + lane * 4, &buf[w][0][c * 256]);

    float dsum[4];
    #pragma unroll
    for (int k = 0; k < 4; k++) {
        if (k < 3) {
            #pragma unroll
            for (int c = 0; c < 8; c++)
                gl_lds(rp[k + 1] + c * 256 + lane * 4, &buf[w][(k + 1) & 1][c * 256]);
            __builtin_amdgcn_s_waitcnt(WAIT_VM8);
        } else {
            __builtin_amdgcn_s_waitcnt(WAIT_VM0);
        }
        const float* r = buf[w][k & 1];
        float acc = 0.f;
        #pragma unroll
        for (int c = 0; c < 8; c++) {
            float4 a = *reinterpret_cast<const float4*>(r + c * 256 + lane * 4);
            acc = fmaf(a.x, va[c].x, acc); acc = fmaf(a.y, va[c].y, acc);
            acc = fmaf(a.z, va[c].z, acc); acc = fmaf(a.w, va[c].w, acc);
        }
        dsum[k] = acc;
    }
    float gate[4];
    #pragma unroll
    for (int k = 0; k < 4; k++) gate[k] = wred(dsum[k]);
    if (lane == 0) {
        float gi = gate[0] + g_p1[wid];
        float gf = gate[1] + g_p1[wid + H];
        float gg = gate[2] + g_p1[wid + 2 * H];
        float go = gate[3] + g_p1[wid + 3 * H];
        float cp = c_s[H + wid];
        float cn = sg(gf) * cp + sg(gi) * tanhf(gg);
        float hn = sg(go) * tanhf(cn);
        out[H + wid]     = hn;   // new_h[1]
        out[3 * H + wid] = cn;   // new_c[1]
        g_h1[wid] = hn;
    }
}

// K3: fused LayerNorm (redundant per block) + head hidden.
// 208 blocks: head k=b>>4, unit o=(b&15)*4+w. W1 rows staged async during LN.
__global__ __launch_bounds__(256) void k3(
    const float* __restrict__ ln_g, const float* __restrict__ ln_b,
    const float* __restrict__ W1, const float* __restrict__ b1)
{
    __shared__ float rows[4][H];
    __shared__ float ht[H];
    __shared__ float red[8];
    __shared__ float mvs[2];
    int tid = threadIdx.x, w = tid >> 6, lane = tid & 63;
    int k = blockIdx.x >> 4;
    int o = (blockIdx.x & 15) * 4 + w;
    const float* rp = W1 + ((long)k * 64 + o) * H;
    #pragma unroll
    for (int c = 0; c < 8; c++) gl_lds(rp + c * 256 + lane * 4, &rows[w][c * 256]);

    float v[8];
    float s = 0.f, s2 = 0.f;
    #pragma unroll
    for (int i = 0; i < 8; i++) {
        float x = g_h1[tid + i * 256];
        v[i] = x; s += x; s2 += x * x;
    }
    s = wred(s); s2 = wred(s2);
    if (lane == 0) { red[w] = s; red[4 + w] = s2; }
    __syncthreads();
    if (tid == 0) {
        float ts = red[0] + red[1] + red[2] + red[3];
        float t2 = red[4] + red[5] + red[6] + red[7];
        float mu = ts / (float)H;
        float var = t2 / (float)H - mu * mu;
        mvs[0] = mu; mvs[1] = rsqrtf(var + 1e-5f);
    }
    __syncthreads();
    float mu = mvs[0], rs = mvs[1];
    #pragma unroll
    for (int i = 0; i < 8; i++) {
        int e = tid + i * 256;
        ht[e] = (v[i] - mu) * rs * ln_g[e] + ln_b[e];
    }
    __syncthreads();

    float acc = 0.f;
    #pragma unroll
    for (int c = 0; c < 8; c++) {
        float4 a = *reinterpret_cast<const float4*>(rows[w] + c * 256 + lane * 4);
        float4 vv = *reinterpret_cast<const float4*>(ht + c * 256 + lane * 4);
        acc = fmaf(a.x, vv.x, acc); acc = fmaf(a.y, vv.y, acc);
        acc = fmaf(a.z, vv.z, acc); acc = fmaf(a.w, vv.w, acc);
    }
    acc = wred(acc);
    if (lane == 0) {
        float r = acc + b1[k * 64 + o];
        g_hid[k * 64 + o] = r > 0.f ? r : 0.f;
    }
}

// K4: head output layer (tiny)
__global__ __launch_bounds__(128) void k4(
    const float* __restrict__ W2, const float* __restrict__ b2,
    float* __restrict__ out)
{
    const int HO[13]  = {5,1,1,1,1,1,1,1,9,1,3,1,1};
    const int OFF[13] = {0,5,6,7,8,9,10,11,12,21,22,25,26};
    int t = threadIdx.x;
    if (t >= 117) return;
    int k = t / 9, p = t % 9;
    if (p >= HO[k]) return;
    const float* wr = W2 + ((long)k * 9 + p) * 64;
    const float* hp = g_hid + k * 64;
    float acc = b2[k * 9 + p];
    #pragma unroll
    for (int o = 0; o < 64; o++) acc = fmaf(hp[o], wr[o], acc);
    out[4 * H + OFF[k] + p] = acc;
}

extern "C" void kernel_launch(void* const* d_in, const int* in_sizes, int n_in,
                              void* d_out, int out_size, void* d_ws, size_t ws_size,
                              hipStream_t stream) {
    const float* lap    = (const float*)d_in[0];
    const int*   idx    = (const int*)  d_in[1];
    const float* h_s    = (const float*)d_in[2];
    const float* c_s    = (const float*)d_in[3];
    const float* e_team = (const float*)d_in[4];
    const float* e_trk  = (const float*)d_in[5];
    const float* e_drv  = (const float*)d_in[6];
    const float* e_cmp  = (const float*)d_in[7];
    const float* Wih0   = (const float*)d_in[8];
    const float* Whh0   = (const float*)d_in[9];
    const float* bih0   = (const float*)d_in[10];
    const float* bhh0   = (const float*)d_in[11];
    const float* Wih1   = (const float*)d_in[12];
    const float* Whh1   = (const float*)d_in[13];
    const float* bih1   = (const float*)d_in[14];
    const float* bhh1   = (const float*)d_in[15];
    const float* ln_g   = (const float*)d_in[16];
    const float* ln_b   = (const float*)d_in[17];
    const float* hW1    = (const float*)d_in[18];
    const float* hb1    = (const float*)d_in[19];
    const float* hW2    = (const float*)d_in[20];
    const float* hb2    = (const float*)d_in[21];
    float* out = (float*)d_out;

    k1<<<512, 256, 0, stream>>>(lap, idx, h_s, c_s, e_team, e_trk, e_drv, e_cmp,
                                Wih0, Whh0, bih0, bhh0, Whh1, bih1, bhh1, out);
    k2<<<512, 256, 0, stream>>>(Wih1, c_s, out);
    k3<<<208, 256, 0, stream>>>(ln_g, ln_b, hW1, hb1);
    k4<<<1, 128, 0, stream>>>(hW2, hb2, out);
}